// Round 4
// baseline (618.756 us; speedup 1.0000x reference)
//
#include <hip/hip_runtime.h>

#define M_DIM 8192
#define N_DIM 4096
#define K_DIM 4096

typedef __attribute__((ext_vector_type(8))) __bf16 bf16x8;
typedef __attribute__((ext_vector_type(4))) __bf16 bf16x4;
typedef __attribute__((ext_vector_type(4))) float floatx4;

// ---------- async global->LDS, 16B per lane (wave-uniform LDS base) ----------
__device__ __forceinline__ void async_copy16(const void* g, void* l) {
    __builtin_amdgcn_global_load_lds(
        (const __attribute__((address_space(1))) void*)g,
        (__attribute__((address_space(3))) void*)l,
        16, 0, 0);
}

// 32-bit LDS byte address for inline-asm ds_read (compiler-invisible LDS read)
__device__ __forceinline__ unsigned lds_addr(const void* p) {
    return (unsigned)(unsigned long long)(const __attribute__((address_space(3))) void*)p;
}
// ds_read_b128 with compile-time offset immediate
#define DSRD(dst, addr, OFF) \
    asm volatile("ds_read_b128 %0, %1 offset:" #OFF : "=v"(dst) : "v"(addr))

#define SB  __builtin_amdgcn_sched_barrier(0)
#define SP1 __builtin_amdgcn_s_setprio(1)
#define SP0 __builtin_amdgcn_s_setprio(0)

// ---------- deterministic reductions (fp64) ----------
__device__ __forceinline__ double wave_reduce_d(double v) {
    #pragma unroll
    for (int o = 32; o > 0; o >>= 1) v += __shfl_down(v, o, 64);
    return v;
}
__device__ __forceinline__ unsigned wave_reduce_u(unsigned v) {
    #pragma unroll
    for (int o = 32; o > 0; o >>= 1) v += __shfl_down(v, o, 64);
    return v;
}

// K1 (fused): blocks [0,2048) -> partial sums of |W|; blocks [2048,10240) -> x fp32->bf16
__global__ __launch_bounds__(256) void k_pre(const float4* __restrict__ w4,
                                             double* __restrict__ part,
                                             const float4* __restrict__ x4,
                                             bf16x4* __restrict__ xb) {
    const int tid = threadIdx.x;
    if (blockIdx.x < 2048) {
        int idx = blockIdx.x * 256 + tid;
        double s = 0.0;
        #pragma unroll
        for (int it = 0; it < 8; ++it) {
            float4 v = w4[idx + it * (2048 * 256)];
            s += (double)fabsf(v.x) + (double)fabsf(v.y) +
                 (double)fabsf(v.z) + (double)fabsf(v.w);
        }
        s = wave_reduce_d(s);
        __shared__ double sm[4];
        if ((tid & 63) == 0) sm[tid >> 6] = s;
        __syncthreads();
        if (tid == 0) part[blockIdx.x] = sm[0] + sm[1] + sm[2] + sm[3];
    } else {
        int idx = (blockIdx.x - 2048) * 256 + tid;
        #pragma unroll
        for (int it = 0; it < 4; ++it) {
            int i = idx + it * (8192 * 256);
            float4 v = x4[i];
            bf16x4 o;
            o[0] = (__bf16)v.x; o[1] = (__bf16)v.y;
            o[2] = (__bf16)v.z; o[3] = (__bf16)v.w;
            xb[i] = o;
        }
    }
}

// K2: block-redundant delta from part[2048]; quantize; masked partial sums.
// Per-element math BIT-IDENTICAL to the passing kernel (f64 delta/compare).
__global__ __launch_bounds__(256) void k_quant(const float4* __restrict__ w4,
                                               bf16x4* __restrict__ tern,
                                               const double* __restrict__ part,
                                               double* __restrict__ scal,
                                               double* __restrict__ pm,
                                               unsigned* __restrict__ pc) {
    const int tid = threadIdx.x;
    double s = 0.0;
    #pragma unroll
    for (int i = 0; i < 8; ++i) s += part[tid + i * 256];
    s = wave_reduce_d(s);
    __shared__ double sm[4];
    if ((tid & 63) == 0) sm[tid >> 6] = s;
    __syncthreads();
    const double mean = (sm[0] + sm[1] + sm[2] + sm[3]) * (1.0 / 16777216.0);
    const double delta = 0.7 * mean;
    if (blockIdx.x == 0 && tid == 0) scal[0] = mean;

    int idx = blockIdx.x * 256 + tid;
    double msum = 0.0;
    unsigned cnt = 0;
    #pragma unroll
    for (int it = 0; it < 8; ++it) {
        int i = idx + it * (2048 * 256);
        float4 v = w4[i];
        float e[4] = {v.x, v.y, v.z, v.w};
        bf16x4 o;
        #pragma unroll
        for (int c = 0; c < 4; ++c) {
            float wv = e[c];
            float t = ((double)wv > delta) ? 1.0f
                    : (((double)wv < -delta) ? -1.0f : 0.0f);
            if (t != 0.0f) { msum += (double)fabsf(wv); cnt++; }
            o[c] = (__bf16)t;
        }
        tern[i] = o;
    }
    msum = wave_reduce_d(msum);
    cnt  = wave_reduce_u(cnt);
    __shared__ double smd[4];
    __shared__ unsigned smu[4];
    if ((tid & 63) == 0) { smd[tid >> 6] = msum; smu[tid >> 6] = cnt; }
    __syncthreads();
    if (tid == 0) {
        pm[blockIdx.x] = smd[0] + smd[1] + smd[2] + smd[3];
        pc[blockIdx.x] = smu[0] + smu[1] + smu[2] + smu[3];
    }
}

// ---------- GEMM: C[m][n] = alpha * sum_k A[m][k]*B[n][k] + bias[n] ----------
// R2 geometry (256x256, 8 waves 2Mx4N, BK=32, 4-slot LDS ring, counted vmcnt,
// proven 0-conflict XOR swizzle) + NEW schedule: register double-buffered
// fragments with a pinned textual interleave — tile n's 32 MFMA overlap
// tile n+1's 12 ds_read_b128 and tile n+3's 4 global_load_lds, in groups
// fenced by sched_barrier(0). One lgkmcnt(0) per tile (top), vmcnt never 0
// in the main loop.
__global__ __launch_bounds__(512, 2) void ternary_gemm(
    const __bf16* __restrict__ A,    // M x K (x in bf16)
    const __bf16* __restrict__ B,    // N x K (ternary in bf16)
    const float*  __restrict__ bias, // N
    const double* __restrict__ scal, // [0] = mean|w| fallback
    const double* __restrict__ pm,   // 2048 masked partial sums
    const unsigned* __restrict__ pc, // 2048 masked partial counts
    float* __restrict__ C)           // M x N
{
    __shared__ __attribute__((aligned(128))) __bf16 As[4][8192];  // 64 KB
    __shared__ __attribute__((aligned(128))) __bf16 Bs[4][8192];  // 64 KB
    __shared__ double smd[8];
    __shared__ unsigned smu[8];

    const int tid  = threadIdx.x;
    const int w    = tid >> 6;
    const int lane = tid & 63;
    const int quad = lane >> 4;
    const int l16  = lane & 15;
    const int wr = w >> 2;   // 0..1 -> rows wr*128
    const int wc = w & 3;    // 0..3 -> cols wc*64

    // bijective XCD swizzle (512 % 8 == 0)
    const int id = (blockIdx.x & 7) * 64 + (blockIdx.x >> 3);
    const int br = id >> 4;  // 0..31 M tile
    const int bc = id & 15;  // 0..15 N tile

    // staging: chunk = 16 rows x 32 cols (1 KB); A,B each 16 chunks/tile.
    // wave w stages chunks {2w, 2w+1} of A and of B.
    // XOR swizzle: LDS pos (lane&3) holds global octet (lane&3)^((srow>>1)&3).
    const int srow = lane >> 2;
    const int scol = ((lane & 3) ^ ((srow >> 1) & 3)) * 8;

    const __bf16* gA0 = A + (size_t)(br * 256 + (2 * w + 0) * 16 + srow) * K_DIM + scol;
    const __bf16* gA1 = A + (size_t)(br * 256 + (2 * w + 1) * 16 + srow) * K_DIM + scol;
    const __bf16* gB0 = B + (size_t)(bc * 256 + (2 * w + 0) * 16 + srow) * K_DIM + scol;
    const __bf16* gB1 = B + (size_t)(bc * 256 + (2 * w + 1) * 16 + srow) * K_DIM + scol;

    floatx4 acc[8][4] = {};

    // fragment read: octet for (quad, row l16) sits at position quad^((l16>>1)&3)
    const int swz   = (quad ^ ((l16 >> 1) & 3)) * 8;
    const int a_off = (wr * 128 + l16) * 64 + swz * 2;  // bytes
    const int b_off = (wc * 64  + l16) * 64 + swz * 2;  // bytes

    const unsigned aS0 = lds_addr(&As[0][0]) + (unsigned)a_off;
    const unsigned aS1 = aS0 + 16384;
    const unsigned aS2 = aS0 + 32768;
    const unsigned aS3 = aS0 + 49152;
    const unsigned bS0 = lds_addr(&Bs[0][0]) + (unsigned)b_off;
    const unsigned bS1 = bS0 + 16384;
    const unsigned bS2 = bS0 + 32768;
    const unsigned bS3 = bS0 + 49152;

    // register double-buffer of fragments (ping-pong sets 0/1)
    bf16x8 rA0[8], rA1[8], rB0[4], rB1[4];

#define STAGE2A(stg_, SLOT) do {                                   \
        const int _so = (stg_) * 32;                               \
        async_copy16(gA0 + _so, &As[SLOT][(2 * w + 0) * 512]);     \
        async_copy16(gA1 + _so, &As[SLOT][(2 * w + 1) * 512]);     \
    } while (0)
#define STAGE2B(stg_, SLOT) do {                                   \
        const int _so = (stg_) * 32;                               \
        async_copy16(gB0 + _so, &Bs[SLOT][(2 * w + 0) * 512]);     \
        async_copy16(gB1 + _so, &Bs[SLOT][(2 * w + 1) * 512]);     \
    } while (0)

#define MF4(CUR, I) do {                                                        \
        acc[I][0] = __builtin_amdgcn_mfma_f32_16x16x32_bf16(rA##CUR[I], rB##CUR[0], acc[I][0], 0, 0, 0); \
        acc[I][1] = __builtin_amdgcn_mfma_f32_16x16x32_bf16(rA##CUR[I], rB##CUR[1], acc[I][1], 0, 0, 0); \
        acc[I][2] = __builtin_amdgcn_mfma_f32_16x16x32_bf16(rA##CUR[I], rB##CUR[2], acc[I][2], 0, 0, 0); \
        acc[I][3] = __builtin_amdgcn_mfma_f32_16x16x32_bf16(rA##CUR[I], rB##CUR[3], acc[I][3], 0, 0, 0); \
    } while (0)

// Iteration n: MFMA tile n from reg set CUR; ds_read tile n+1 (slot (n+1)&3,
// bases AN/BN) into set NXT; stage tile stg_=n+3 into slot (n+3)&3.
#define ITER(AN, BN, SSLOT, CUR, NXT, stg_, VMN, DO_DSR, DO_STAGE) do {        \
        asm volatile("s_waitcnt vmcnt(" #VMN ")" ::: "memory");                \
        __builtin_amdgcn_s_barrier();                                          \
        asm volatile("s_waitcnt lgkmcnt(0)" ::: "memory");                     \
        SB;                                                                    \
        SP1; MF4(CUR, 0); SP0; SB;                                             \
        if (DO_DSR) { DSRD(rA##NXT[0], AN, 0);                                 \
                      DSRD(rA##NXT[1], AN, 1024);                              \
                      DSRD(rA##NXT[2], AN, 2048); }                            \
        SB;                                                                    \
        SP1; MF4(CUR, 1); SP0; SB;                                             \
        if (DO_DSR) { DSRD(rA##NXT[3], AN, 3072);                              \
                      DSRD(rB##NXT[0], BN, 0);                                 \
                      DSRD(rB##NXT[1], BN, 1024); }                            \
        SB;                                                                    \
        SP1; MF4(CUR, 2); SP0; SB;                                             \
        if (DO_DSR) { DSRD(rB##NXT[2], BN, 2048);                              \
                      DSRD(rB##NXT[3], BN, 3072);                              \
                      DSRD(rA##NXT[4], AN, 4096); }                            \
        SB;                                                                    \
        SP1; MF4(CUR, 3); SP0; SB;                                             \
        if (DO_DSR) { DSRD(rA##NXT[5], AN, 5120);                              \
                      DSRD(rA##NXT[6], AN, 6144);                              \
                      DSRD(rA##NXT[7], AN, 7168); }                            \
        SB;                                                                    \
        SP1; MF4(CUR, 4); SP0; SB;                                             \
        if (DO_STAGE) STAGE2A(stg_, SSLOT);                                    \
        SB;                                                                    \
        SP1; MF4(CUR, 5); SP0; SB;                                             \
        if (DO_STAGE) STAGE2B(stg_, SSLOT);                                    \
        SB;                                                                    \
        SP1; MF4(CUR, 6); MF4(CUR, 7); SP0;                                    \
        SB;                                                                    \
    } while (0)

    // prologue: stage tiles 0,1,2 (12 loads/wave); wait tile 0; preload regs
    STAGE2A(0, 0); STAGE2B(0, 0);
    STAGE2A(1, 1); STAGE2B(1, 1);
    STAGE2A(2, 2); STAGE2B(2, 2);
    asm volatile("s_waitcnt vmcnt(8)" ::: "memory");
    __builtin_amdgcn_s_barrier();
    DSRD(rA0[0], aS0, 0);    DSRD(rA0[1], aS0, 1024);
    DSRD(rA0[2], aS0, 2048); DSRD(rA0[3], aS0, 3072);
    DSRD(rA0[4], aS0, 4096); DSRD(rA0[5], aS0, 5120);
    DSRD(rA0[6], aS0, 6144); DSRD(rA0[7], aS0, 7168);
    DSRD(rB0[0], bS0, 0);    DSRD(rB0[1], bS0, 1024);
    DSRD(rB0[2], bS0, 2048); DSRD(rB0[3], bS0, 3072);

    // main loop: n = 0..123 (MFMA tile n, read n+1, stage n+3; vmcnt(4) counted)
    for (int n = 0; n < 124; n += 4) {
        ITER(aS1, bS1, 3, 0, 1, n + 3, 4, 1, 1);
        ITER(aS2, bS2, 0, 1, 0, n + 4, 4, 1, 1);
        ITER(aS3, bS3, 1, 0, 1, n + 5, 4, 1, 1);
        ITER(aS0, bS0, 2, 1, 0, n + 6, 4, 1, 1);
    }
    // tail: n = 124..127
    ITER(aS1, bS1, 3, 0, 1, 127, 4, 1, 1);   // n=124: stage tile 127
    ITER(aS2, bS2, 0, 1, 0, 0,   4, 1, 0);   // n=125
    ITER(aS3, bS3, 0, 0, 1, 0,   0, 1, 0);   // n=126: drain for tile 127
    ITER(aS0, bS0, 0, 1, 0, 0,   0, 0, 0);   // n=127: compute only

#undef ITER
#undef MF4
#undef STAGE2A
#undef STAGE2B

    // block-redundant alpha reduce (deterministic, identical in every block)
    double s = 0.0; unsigned c = 0;
    #pragma unroll
    for (int i = 0; i < 4; ++i) { s += pm[tid + i * 512]; c += pc[tid + i * 512]; }
    s = wave_reduce_d(s);
    c = wave_reduce_u(c);
    if (lane == 0) { smd[w] = s; smu[w] = c; }
    __syncthreads();
    double ms = 0.0; unsigned ct = 0;
    #pragma unroll
    for (int i = 0; i < 8; ++i) { ms += smd[i]; ct += smu[i]; }
    const float alpha = (float)(ct > 0 ? ms / (double)ct : scal[0]);

    float bv[4];
    #pragma unroll
    for (int j = 0; j < 4; ++j)
        bv[j] = bias[bc * 256 + wc * 64 + j * 16 + l16];

    // C/D layout (16x16x32): col = lane&15, row = quad*4 + reg
    #pragma unroll
    for (int i = 0; i < 8; ++i) {
        const int row0 = br * 256 + wr * 128 + i * 16 + quad * 4;
        #pragma unroll
        for (int j = 0; j < 4; ++j) {
            const int col = bc * 256 + wc * 64 + j * 16 + l16;
            #pragma unroll
            for (int r = 0; r < 4; ++r)
                C[(size_t)(row0 + r) * N_DIM + col] = acc[i][j][r] * alpha + bv[j];
        }
    }
}

extern "C" void kernel_launch(void* const* d_in, const int* in_sizes, int n_in,
                              void* d_out, int out_size, void* d_ws, size_t ws_size,
                              hipStream_t stream) {
    const float* x    = (const float*)d_in[0];  // (8192, 4096) fp32
    const float* w    = (const float*)d_in[1];  // (4096, 4096) fp32
    const float* bias = (const float*)d_in[2];  // (4096,) fp32
    float* out = (float*)d_out;                 // (8192, 4096) fp32

    char* ws = (char*)d_ws;
    double*   d_scal = (double*)ws;               // [0] = mean|w|
    double*   part   = (double*)(ws + 64);        // 2048 doubles
    double*   pm     = (double*)(ws + 16448);     // 2048 doubles
    unsigned* pc     = (unsigned*)(ws + 32832);   // 2048 uints
    __bf16*   xb     = (__bf16*)(ws + 65536);                                   // 64 MB
    __bf16*   tern   = (__bf16*)(ws + 65536 + (size_t)M_DIM * K_DIM * 2);       // 32 MB

    k_pre<<<10240, 256, 0, stream>>>((const float4*)w, part, (const float4*)x, (bf16x4*)xb);
    k_quant<<<2048, 256, 0, stream>>>((const float4*)w, (bf16x4*)tern, part, d_scal, pm, pc);

    ternary_gemm<<<512, 512, 0, stream>>>(xb, tern, bias, d_scal, pm, pc, out);
}

// Round 5
// 547.268 us; speedup vs baseline: 1.1306x; 1.1306x over previous
//
#include <hip/hip_runtime.h>

#define M_DIM 8192
#define N_DIM 4096
#define K_DIM 4096

typedef __attribute__((ext_vector_type(8))) __bf16 bf16x8;
typedef __attribute__((ext_vector_type(4))) __bf16 bf16x4;
typedef __attribute__((ext_vector_type(4))) float floatx4;

// ---------- async global->LDS, 16B per lane (wave-uniform LDS base) ----------
__device__ __forceinline__ void async_copy16(const void* g, void* l) {
    __builtin_amdgcn_global_load_lds(
        (const __attribute__((address_space(1))) void*)g,
        (__attribute__((address_space(3))) void*)l,
        16, 0, 0);
}

// 32-bit LDS byte address for inline-asm ds_read (compiler-invisible LDS read)
__device__ __forceinline__ unsigned lds_addr(const void* p) {
    return (unsigned)(unsigned long long)(const __attribute__((address_space(3))) void*)p;
}
// ds_read_b128 with compile-time offset immediate
#define DSRD(dst, addr, OFF) \
    asm volatile("ds_read_b128 %0, %1 offset:" #OFF : "=v"(dst) : "v"(addr))

#define SB  __builtin_amdgcn_sched_barrier(0)
#define SP1 __builtin_amdgcn_s_setprio(1)
#define SP0 __builtin_amdgcn_s_setprio(0)

// ---------- deterministic reductions (fp64) ----------
__device__ __forceinline__ double wave_reduce_d(double v) {
    #pragma unroll
    for (int o = 32; o > 0; o >>= 1) v += __shfl_down(v, o, 64);
    return v;
}
__device__ __forceinline__ unsigned wave_reduce_u(unsigned v) {
    #pragma unroll
    for (int o = 32; o > 0; o >>= 1) v += __shfl_down(v, o, 64);
    return v;
}

// K1 (fused): blocks [0,2048) -> partial sums of |W|; blocks [2048,10240) -> x fp32->bf16
__global__ __launch_bounds__(256) void k_pre(const float4* __restrict__ w4,
                                             double* __restrict__ part,
                                             const float4* __restrict__ x4,
                                             bf16x4* __restrict__ xb) {
    const int tid = threadIdx.x;
    if (blockIdx.x < 2048) {
        int idx = blockIdx.x * 256 + tid;
        double s = 0.0;
        #pragma unroll
        for (int it = 0; it < 8; ++it) {
            float4 v = w4[idx + it * (2048 * 256)];
            s += (double)fabsf(v.x) + (double)fabsf(v.y) +
                 (double)fabsf(v.z) + (double)fabsf(v.w);
        }
        s = wave_reduce_d(s);
        __shared__ double sm[4];
        if ((tid & 63) == 0) sm[tid >> 6] = s;
        __syncthreads();
        if (tid == 0) part[blockIdx.x] = sm[0] + sm[1] + sm[2] + sm[3];
    } else {
        int idx = (blockIdx.x - 2048) * 256 + tid;
        #pragma unroll
        for (int it = 0; it < 4; ++it) {
            int i = idx + it * (8192 * 256);
            float4 v = x4[i];
            bf16x4 o;
            o[0] = (__bf16)v.x; o[1] = (__bf16)v.y;
            o[2] = (__bf16)v.z; o[3] = (__bf16)v.w;
            xb[i] = o;
        }
    }
}

// K2: block-redundant delta from part[2048]; quantize; masked partial sums.
// Per-element math BIT-IDENTICAL to the passing kernel (f64 delta/compare).
__global__ __launch_bounds__(256) void k_quant(const float4* __restrict__ w4,
                                               bf16x4* __restrict__ tern,
                                               const double* __restrict__ part,
                                               double* __restrict__ scal,
                                               double* __restrict__ pm,
                                               unsigned* __restrict__ pc) {
    const int tid = threadIdx.x;
    double s = 0.0;
    #pragma unroll
    for (int i = 0; i < 8; ++i) s += part[tid + i * 256];
    s = wave_reduce_d(s);
    __shared__ double sm[4];
    if ((tid & 63) == 0) sm[tid >> 6] = s;
    __syncthreads();
    const double mean = (sm[0] + sm[1] + sm[2] + sm[3]) * (1.0 / 16777216.0);
    const double delta = 0.7 * mean;
    if (blockIdx.x == 0 && tid == 0) scal[0] = mean;

    int idx = blockIdx.x * 256 + tid;
    double msum = 0.0;
    unsigned cnt = 0;
    #pragma unroll
    for (int it = 0; it < 8; ++it) {
        int i = idx + it * (2048 * 256);
        float4 v = w4[i];
        float e[4] = {v.x, v.y, v.z, v.w};
        bf16x4 o;
        #pragma unroll
        for (int c = 0; c < 4; ++c) {
            float wv = e[c];
            float t = ((double)wv > delta) ? 1.0f
                    : (((double)wv < -delta) ? -1.0f : 0.0f);
            if (t != 0.0f) { msum += (double)fabsf(wv); cnt++; }
            o[c] = (__bf16)t;
        }
        tern[i] = o;
    }
    msum = wave_reduce_d(msum);
    cnt  = wave_reduce_u(cnt);
    __shared__ double smd[4];
    __shared__ unsigned smu[4];
    if ((tid & 63) == 0) { smd[tid >> 6] = msum; smu[tid >> 6] = cnt; }
    __syncthreads();
    if (tid == 0) {
        pm[blockIdx.x] = smd[0] + smd[1] + smd[2] + smd[3];
        pc[blockIdx.x] = smu[0] + smu[1] + smu[2] + smu[3];
    }
}

// ---------- GEMM: C[m][n] = alpha * sum_k A[m][k]*B[n][k] + bias[n] ----------
// m201-style 8-phase schedule on R2 geometry: 256x256 tile, 8 waves (2Mx4N,
// per-wave 128x64), BK=32 slots, 4-slot LDS ring (128 KiB). Each slot = 2
// phases of 16 MFMA; per phase {issue next-half ds_reads (+stage in alpha) ->
// barrier -> counted lgkm -> setprio(1) 16 MFMA setprio(0) -> barrier}.
// vmcnt(8) once per slot (never 0 in-loop). Counted lgkm makes reads overlap
// the MFMA cluster; double-barrier bounds inter-wave skew to one phase.
// LDS chunk layout + XOR swizzle identical to R0/R2 (measured 0 conflicts).
__global__ __launch_bounds__(512, 2) void ternary_gemm(
    const __bf16* __restrict__ A,    // M x K (x in bf16)
    const __bf16* __restrict__ B,    // N x K (ternary in bf16)
    const float*  __restrict__ bias, // N
    const double* __restrict__ scal, // [0] = mean|w| fallback
    const double* __restrict__ pm,   // 2048 masked partial sums
    const unsigned* __restrict__ pc, // 2048 masked partial counts
    float* __restrict__ C)           // M x N
{
    __shared__ __attribute__((aligned(128))) __bf16 As[4][8192];  // 64 KB
    __shared__ __attribute__((aligned(128))) __bf16 Bs[4][8192];  // 64 KB
    __shared__ double smd[8];
    __shared__ unsigned smu[8];

    const int tid  = threadIdx.x;
    const int w    = tid >> 6;
    const int lane = tid & 63;
    const int quad = lane >> 4;
    const int l16  = lane & 15;
    const int wr = w >> 2;   // 0..1 -> rows wr*128
    const int wc = w & 3;    // 0..3 -> cols wc*64

    // bijective XCD swizzle (512 % 8 == 0)
    const int id = (blockIdx.x & 7) * 64 + (blockIdx.x >> 3);
    const int br = id >> 4;  // 0..31 M tile
    const int bc = id & 15;  // 0..15 N tile

    // staging: chunk = 16 rows x 32 cols (1 KB); A,B each 16 chunks/slot.
    // wave w stages chunks {2w, 2w+1} of A and of B.
    // XOR swizzle: LDS pos (lane&3) holds global octet (lane&3)^((srow>>1)&3).
    const int srow = lane >> 2;
    const int scol = ((lane & 3) ^ ((srow >> 1) & 3)) * 8;

    const __bf16* gA0 = A + (size_t)(br * 256 + (2 * w + 0) * 16 + srow) * K_DIM + scol;
    const __bf16* gA1 = A + (size_t)(br * 256 + (2 * w + 1) * 16 + srow) * K_DIM + scol;
    const __bf16* gB0 = B + (size_t)(bc * 256 + (2 * w + 0) * 16 + srow) * K_DIM + scol;
    const __bf16* gB1 = B + (size_t)(bc * 256 + (2 * w + 1) * 16 + srow) * K_DIM + scol;

    floatx4 acc[8][4] = {};

    // fragment read: octet for (quad, row l16) sits at position quad^((l16>>1)&3)
    const int swz   = (quad ^ ((l16 >> 1) & 3)) * 8;
    const int a_off = (wr * 128 + l16) * 64 + swz * 2;  // bytes
    const int b_off = (wc * 64  + l16) * 64 + swz * 2;  // bytes

    // ring-slot fragment base addresses
    const unsigned aR0 = lds_addr(&As[0][0]) + (unsigned)a_off;
    const unsigned aR1 = aR0 + 16384;
    const unsigned aR2 = aR0 + 32768;
    const unsigned aR3 = aR0 + 49152;
    const unsigned bR0 = lds_addr(&Bs[0][0]) + (unsigned)b_off;
    const unsigned bR1 = bR0 + 16384;
    const unsigned bR2 = bR0 + 32768;
    const unsigned bR3 = bR0 + 49152;

    // register ping-pong fragment sets (all indices literal after unroll)
    bf16x8 aL0[4], aL1[4], aH0[4], aH1[4], bb0[4], bb1[4];

#define STAGE2A(stg_, SLOT) do {                                   \
        const int _so = (stg_) * 32;                               \
        async_copy16(gA0 + _so, &As[SLOT][(2 * w + 0) * 512]);     \
        async_copy16(gA1 + _so, &As[SLOT][(2 * w + 1) * 512]);     \
    } while (0)
#define STAGE2B(stg_, SLOT) do {                                   \
        const int _so = (stg_) * 32;                               \
        async_copy16(gB0 + _so, &Bs[SLOT][(2 * w + 0) * 512]);     \
        async_copy16(gB1 + _so, &Bs[SLOT][(2 * w + 1) * 512]);     \
    } while (0)

#define MFQ(AF, BF, BASE) do {                                                 \
        _Pragma("unroll")                                                      \
        for (int i = 0; i < 4; ++i)                                            \
            _Pragma("unroll")                                                  \
            for (int j = 0; j < 4; ++j)                                        \
                acc[(BASE) + i][j] = __builtin_amdgcn_mfma_f32_16x16x32_bf16(  \
                    AF[i], BF[j], acc[(BASE) + i][j], 0, 0, 0);                \
    } while (0)

// One BK=32 slot = two phases.
// AS/BS: this slot's frag bases; AS2/BS2: next slot's. P: this slot's reg
// parity; Q = 1-P. STG/SSLOT: K-index and ring slot to stage. VMN: counted
// vmcnt for this slot's staging guarantee.
#define SLOT(AS, BS, AS2, BS2, P, Q, STG, SSLOT, VMN, DO_STAGE, DO_READ) do {  \
        /* ---- phase alpha: MFMA acc[0..3] (aL,b); read aH; stage ---- */     \
        DSRD(aH##P[0], AS, 4096); DSRD(aH##P[1], AS, 5120);                    \
        DSRD(aH##P[2], AS, 6144); DSRD(aH##P[3], AS, 7168);                    \
        if (DO_STAGE) { STAGE2A(STG, SSLOT); STAGE2B(STG, SSLOT); }            \
        asm volatile("s_waitcnt vmcnt(" #VMN ")" ::: "memory");                \
        __builtin_amdgcn_s_barrier();                                          \
        asm volatile("s_waitcnt lgkmcnt(4)" ::: "memory");                     \
        SB;                                                                    \
        SP1; MFQ(aL##P, bb##P, 0); SP0; SB;                                    \
        __builtin_amdgcn_s_barrier();                                          \
        /* ---- phase beta: MFMA acc[4..7] (aH,b); read next aL/b ---- */      \
        if (DO_READ) {                                                         \
            DSRD(aL##Q[0], AS2, 0);    DSRD(aL##Q[1], AS2, 1024);              \
            DSRD(aL##Q[2], AS2, 2048); DSRD(aL##Q[3], AS2, 3072);              \
            DSRD(bb##Q[0], BS2, 0);    DSRD(bb##Q[1], BS2, 1024);              \
            DSRD(bb##Q[2], BS2, 2048); DSRD(bb##Q[3], BS2, 3072);              \
        }                                                                      \
        __builtin_amdgcn_s_barrier();                                          \
        if (DO_READ) { asm volatile("s_waitcnt lgkmcnt(8)" ::: "memory"); }    \
        else         { asm volatile("s_waitcnt lgkmcnt(0)" ::: "memory"); }    \
        SB;                                                                    \
        SP1; MFQ(aH##P, bb##P, 4); SP0; SB;                                    \
        __builtin_amdgcn_s_barrier();                                          \
    } while (0)

    // prologue: stage slots 0,1,2 (12 copies/wave); ensure slot 0; preload regs
    STAGE2A(0, 0); STAGE2B(0, 0);
    STAGE2A(1, 1); STAGE2B(1, 1);
    STAGE2A(2, 2); STAGE2B(2, 2);
    asm volatile("s_waitcnt vmcnt(8)" ::: "memory");
    __builtin_amdgcn_s_barrier();
    DSRD(aL0[0], aR0, 0);    DSRD(aL0[1], aR0, 1024);
    DSRD(aL0[2], aR0, 2048); DSRD(aL0[3], aR0, 3072);
    DSRD(bb0[0], bR0, 0);    DSRD(bb0[1], bR0, 1024);
    DSRD(bb0[2], bR0, 2048); DSRD(bb0[3], bR0, 3072);

    // main loop: slots 0..123 (ring period 4, parity period 2)
    for (int s = 0; s < 124; s += 4) {
        SLOT(aR0, bR0, aR1, bR1, 0, 1, s + 3, 3, 8, 1, 1);
        SLOT(aR1, bR1, aR2, bR2, 1, 0, s + 4, 0, 8, 1, 1);
        SLOT(aR2, bR2, aR3, bR3, 0, 1, s + 5, 1, 8, 1, 1);
        SLOT(aR3, bR3, aR0, bR0, 1, 0, s + 6, 2, 8, 1, 1);
    }
    // tail: slots 124..127
    SLOT(aR0, bR0, aR1, bR1, 0, 1, 127, 3, 8, 1, 1);  // 124: stage 127
    SLOT(aR1, bR1, aR2, bR2, 1, 0, 0,   0, 4, 0, 1);  // 125
    SLOT(aR2, bR2, aR3, bR3, 0, 1, 0,   0, 0, 0, 1);  // 126
    SLOT(aR3, bR3, aR0, bR0, 1, 0, 0,   0, 0, 0, 0);  // 127: no next read

#undef SLOT
#undef MFQ
#undef STAGE2A
#undef STAGE2B

    // block-redundant alpha reduce (deterministic, identical in every block)
    double s = 0.0; unsigned c = 0;
    #pragma unroll
    for (int i = 0; i < 4; ++i) { s += pm[tid + i * 512]; c += pc[tid + i * 512]; }
    s = wave_reduce_d(s);
    c = wave_reduce_u(c);
    if (lane == 0) { smd[w] = s; smu[w] = c; }
    __syncthreads();
    double ms = 0.0; unsigned ct = 0;
    #pragma unroll
    for (int i = 0; i < 8; ++i) { ms += smd[i]; ct += smu[i]; }
    const float alpha = (float)(ct > 0 ? ms / (double)ct : scal[0]);

    float bv[4];
    #pragma unroll
    for (int j = 0; j < 4; ++j)
        bv[j] = bias[bc * 256 + wc * 64 + j * 16 + l16];

    // C/D layout (16x16x32): col = lane&15, row = quad*4 + reg
    #pragma unroll
    for (int i = 0; i < 8; ++i) {
        const int row0 = br * 256 + wr * 128 + i * 16 + quad * 4;
        #pragma unroll
        for (int j = 0; j < 4; ++j) {
            const int col = bc * 256 + wc * 64 + j * 16 + l16;
            #pragma unroll
            for (int r = 0; r < 4; ++r)
                C[(size_t)(row0 + r) * N_DIM + col] = acc[i][j][r] * alpha + bv[j];
        }
    }
}

extern "C" void kernel_launch(void* const* d_in, const int* in_sizes, int n_in,
                              void* d_out, int out_size, void* d_ws, size_t ws_size,
                              hipStream_t stream) {
    const float* x    = (const float*)d_in[0];  // (8192, 4096) fp32
    const float* w    = (const float*)d_in[1];  // (4096, 4096) fp32
    const float* bias = (const float*)d_in[2];  // (4096,) fp32
    float* out = (float*)d_out;                 // (8192, 4096) fp32

    char* ws = (char*)d_ws;
    double*   d_scal = (double*)ws;               // [0] = mean|w|
    double*   part   = (double*)(ws + 64);        // 2048 doubles
    double*   pm     = (double*)(ws + 16448);     // 2048 doubles
    unsigned* pc     = (unsigned*)(ws + 32832);   // 2048 uints
    __bf16*   xb     = (__bf16*)(ws + 65536);                                   // 64 MB
    __bf16*   tern   = (__bf16*)(ws + 65536 + (size_t)M_DIM * K_DIM * 2);       // 32 MB

    k_pre<<<10240, 256, 0, stream>>>((const float4*)w, part, (const float4*)x, (bf16x4*)xb);
    k_quant<<<2048, 256, 0, stream>>>((const float4*)w, (bf16x4*)tern, part, d_scal, pm, pc);

    ternary_gemm<<<512, 512, 0, stream>>>(xb, tern, bias, d_scal, pm, pc, out);
}